// Round 1
// 400.097 us; speedup vs baseline: 1.0104x; 1.0104x over previous
//
#include <hip/hip_runtime.h>

// Problem constants (from reference)
#define N_NODES 200000
#define DIM 128                 // node / nig embedding dim
#define HID 256                 // hidden dim
#define BATCH 8192
#define SIDE_FLOATS (N_NODES * DIM)   // 25,600,000 floats per side
#define SIDE_F4 (SIDE_FLOATS / 4)     // 6,400,000 float4 per side

typedef float vf4 __attribute__((ext_vector_type(4)));  // native vector: OK for nontemporal builtins

#define SETUP_BLOCKS 514              // 2 sides x (256 Mf rows + 1 bias)
#define COPY_BLOCKS_PER_SIDE 4096
#define COPY_THREADS_PER_SIDE (COPY_BLOCKS_PER_SIDE * 256)   // 1,048,576

// ---------------------------------------------------------------------------
// Kernel A: weight-fold setup (blocks [0,514)) hidden under a branch-free
// streaming copy prev -> out (blocks [514, 514+8192)). No flags, no LDS on
// the copy path (full 8 blocks/CU occupancy), no dependent flag loads.
//   Mf fold:  node = x @ Mf[0:128] + n @ Mf[128:256] + bias
// ---------------------------------------------------------------------------
__global__ __launch_bounds__(256) void copy_setup_kernel(
    const float* __restrict__ prev0, const float* __restrict__ prev1,
    const float* __restrict__ Wr0, const float* __restrict__ Wn0, const float* __restrict__ Wo0,
    const float* __restrict__ br0, const float* __restrict__ bn0, const float* __restrict__ bo0,
    const float* __restrict__ Wr1, const float* __restrict__ Wn1, const float* __restrict__ Wo1,
    const float* __restrict__ br1, const float* __restrict__ bn1, const float* __restrict__ bo1,
    float* __restrict__ Mf, float* __restrict__ bias,
    float* __restrict__ out)
{
    const int bx  = blockIdx.x;
    const int tid = threadIdx.x;

    if (bx >= SETUP_BLOCKS) {
        // ---- pure streaming copy: grid-stride float4, nontemporal ----
        const int cb   = bx - SETUP_BLOCKS;
        const int side = cb >> 12;                         // 4096 blocks per side
        const int c    = cb & (COPY_BLOCKS_PER_SIDE - 1);
        const vf4* __restrict__ p4 = (const vf4*)(side ? prev1 : prev0);
        vf4* o4 = (vf4*)out + (size_t)side * SIDE_F4;

        int idx = c * 256 + tid;
        // 6,400,000 = 6*1,048,576 + 108,544 -> first 108,544 threads do 7 iters
        #pragma unroll
        for (int i = 0; i < 7; ++i) {
            if (idx < SIDE_F4) {
                vf4 v = __builtin_nontemporal_load(p4 + idx);
                __builtin_nontemporal_store(v, o4 + idx);
            }
            idx += COPY_THREADS_PER_SIDE;
        }
        return;
    }

    // ---- setup: fold affine chain into Mf[side][2*DIM][DIM] + bias[side][DIM]
    const int s = (bx >= 257) ? 1 : 0;
    const int k = bx - s * 257;
    const float* Wr = s ? Wr1 : Wr0;
    const float* Wn = s ? Wn1 : Wn0;
    const float* Wo = s ? Wo1 : Wo0;

    if (k < 2 * DIM) {
        __shared__ float w[HID];
        const float* wrow = (k < DIM) ? (Wr + k * HID) : (Wn + (k - DIM) * HID);
        const float* wo   = (k < DIM) ? Wo : (Wo + HID * DIM);
        w[tid] = wrow[tid];          // 256 threads stage the full 256-wide row
        __syncthreads();
        if (tid < DIM) {
            float acc = 0.f;
            #pragma unroll 8
            for (int h = 0; h < HID; ++h) acc += w[h] * wo[h * DIM + tid];
            Mf[((s << 8) + k) * DIM + tid] = acc;
        }
    } else if (tid < DIM) {
        // bias fold (one block per side, no barrier in this branch)
        const float* br = s ? br1 : br0;
        const float* bn = s ? bn1 : bn0;
        const float* bo = s ? bo1 : bo0;
        float acc = bo[tid];
        for (int h = 0; h < HID; ++h) acc += br[h] * Wo[h * DIM + tid];
        for (int h = 0; h < HID; ++h) acc += bn[h] * Wo[(HID + h) * DIM + tid];
        bias[s * DIM + tid] = acc;
    }
}

// ---------------------------------------------------------------------------
// Kernel B: update path (identical math to the verified fused update branch).
// Stream-ordered after Kernel A, so it simply overwrites the 8192 rows per
// side that A already copied (+8.4 MB redundant write ~ 1.3 us).
// ---------------------------------------------------------------------------
#define RB 32
#define CAT_STRIDE 260   // float4-aligned (260*4%16==0); rg-groups 16 banks apart

__global__ __launch_bounds__(256) void update_kernel(
    const int* __restrict__ ids0, const float* __restrict__ prev0, const float* __restrict__ nig0,
    const int* __restrict__ ids1, const float* __restrict__ prev1, const float* __restrict__ nig1,
    const float* __restrict__ Mf, const float* __restrict__ bias,
    float* __restrict__ out)
{
    const int bx  = blockIdx.x;    // 512 blocks: 256 per side, 32 batch rows each
    const int tid = threadIdx.x;

    const int s = bx >> 8;
    const int*   ids  = s ? ids1  : ids0;
    const float* prev = s ? prev1 : prev0;
    const float* nig  = s ? nig1  : nig0;
    const float* M    = Mf + s * (2 * DIM) * DIM;
    const float* bs   = bias + s * DIM;
    float* outs = out + (size_t)s * SIDE_FLOATS;

    __shared__ int   sid[RB];
    __shared__ float cat[RB][CAT_STRIDE];

    const int b0 = (bx & 255) * RB;

    if (tid < RB) sid[tid] = ids[b0 + tid];
    __syncthreads();

    for (int idx = tid; idx < RB * 64; idx += 256) {
        const int r = idx >> 6;
        const int q = idx & 63;
        float4 v;
        if (q < 32) v = ((const float4*)(prev + (size_t)sid[r] * DIM))[q];
        else        v = ((const float4*)(nig  + (size_t)(b0 + r) * DIM))[q - 32];
        *(float4*)&cat[r][q * 4] = v;
    }
    __syncthreads();

    const int jg = tid & 31;   // 4-col group
    const int rg = tid >> 5;   // 4-row group

    float acc[4][4];
    #pragma unroll
    for (int r = 0; r < 4; ++r)
        #pragma unroll
        for (int c = 0; c < 4; ++c) acc[r][c] = 0.f;

    const float4* M4 = (const float4*)M;
    #pragma unroll 4
    for (int k = 0; k < 2 * DIM; ++k) {
        const float4 m = M4[(k << 5) + jg];
        #pragma unroll
        for (int r = 0; r < 4; ++r) {
            const float a = cat[rg * 4 + r][k];
            acc[r][0] += a * m.x;
            acc[r][1] += a * m.y;
            acc[r][2] += a * m.z;
            acc[r][3] += a * m.w;
        }
    }

    const float4 bj = ((const float4*)bs)[jg];
    #pragma unroll
    for (int r = 0; r < 4; ++r) {
        const int row = sid[rg * 4 + r];
        float4 v;
        v.x = acc[r][0] + bj.x;
        v.y = acc[r][1] + bj.y;
        v.z = acc[r][2] + bj.z;
        v.w = acc[r][3] + bj.w;
        ((float4*)(outs + (size_t)row * DIM))[jg] = v;
    }
}

// ---------------------------------------------------------------------------
extern "C" void kernel_launch(void* const* d_in, const int* in_sizes, int n_in,
                              void* d_out, int out_size, void* d_ws, size_t ws_size,
                              hipStream_t stream) {
    const int*   src_ids   = (const int*)d_in[0];
    const int*   dst_ids   = (const int*)d_in[1];
    const float* src_prev  = (const float*)d_in[2];
    const float* dst_prev  = (const float*)d_in[3];
    const float* src_nig   = (const float*)d_in[4];
    const float* dst_nig   = (const float*)d_in[5];
    const float* W_src_nig     = (const float*)d_in[6];
    const float* b_src_nig     = (const float*)d_in[7];
    const float* W_src_resize  = (const float*)d_in[8];
    const float* b_src_resize  = (const float*)d_in[9];
    const float* W_src_out     = (const float*)d_in[10];
    const float* b_src_out     = (const float*)d_in[11];
    const float* W_dst_nig     = (const float*)d_in[12];
    const float* b_dst_nig     = (const float*)d_in[13];
    const float* W_dst_resize  = (const float*)d_in[14];
    const float* b_dst_resize  = (const float*)d_in[15];
    const float* W_dst_out     = (const float*)d_in[16];
    const float* b_dst_out     = (const float*)d_in[17];

    float* out  = (float*)d_out;
    float* Mf   = (float*)d_ws;                       // 2*256*128 floats
    float* bias = Mf + 2 * (2 * DIM) * DIM;           // 2*128 floats

    // 1) streaming copy prev->out (both sides) with the weight-fold hidden
    //    under it (setup blocks dispatched first, finish in ~4 us)
    copy_setup_kernel<<<SETUP_BLOCKS + 2 * COPY_BLOCKS_PER_SIDE, 256, 0, stream>>>(
        src_prev, dst_prev,
        W_src_resize, W_src_nig, W_src_out, b_src_resize, b_src_nig, b_src_out,
        W_dst_resize, W_dst_nig, W_dst_out, b_dst_resize, b_dst_nig, b_dst_out,
        Mf, bias, out);

    // 2) compute + scatter the 8192 updated rows per side (overwrites)
    update_kernel<<<512, 256, 0, stream>>>(
        src_ids, src_prev, src_nig,
        dst_ids, dst_prev, dst_nig,
        Mf, bias, out);
}

// Round 2
// 387.526 us; speedup vs baseline: 1.0431x; 1.0324x over previous
//
#include <hip/hip_runtime.h>

// Problem constants (from reference)
#define N_NODES 200000
#define DIM 128                 // node / nig embedding dim
#define HID 256                 // hidden dim
#define BATCH 8192
#define SIDE_FLOATS (N_NODES * DIM)   // 25,600,000 floats per side
#define SIDE_F4 (SIDE_FLOATS / 4)     // 6,400,000 float4 per side

typedef float vf4 __attribute__((ext_vector_type(4)));  // native vector: OK for nontemporal builtins

// ---- copy geometry: exact fit, no predication ----
// total float4 = 2 * 6,400,000 = 12,800,000 = COPY_BLOCKS * 256 threads * 8
#define SETUP_BLOCKS 514              // 2 sides x (256 Mf rows + 1 bias)
#define COPY_BLOCKS 6250
#define CHUNK_F4 256                  // float4 moved per block per unrolled step
#define CHUNKS_PER_SIDE 25000         // 6,400,000 / 256 (side boundary is chunk-aligned)

// ---------------------------------------------------------------------------
// Kernel A: weight-fold setup (blocks [0,514)) hidden under a branch-free
// streaming copy prev -> out (blocks [514, 514+6250)).
// Copy: each block moves 8 chunks of 4 KB (32 KB contiguous in out); all 8
// loads are issued before any store (256 KB in flight per CU).
//   Mf fold:  node = x @ Mf[0:128] + n @ Mf[128:256] + bias
// ---------------------------------------------------------------------------
__global__ __launch_bounds__(256) void copy_setup_kernel(
    const float* __restrict__ prev0, const float* __restrict__ prev1,
    const float* __restrict__ Wr0, const float* __restrict__ Wn0, const float* __restrict__ Wo0,
    const float* __restrict__ br0, const float* __restrict__ bn0, const float* __restrict__ bo0,
    const float* __restrict__ Wr1, const float* __restrict__ Wn1, const float* __restrict__ Wo1,
    const float* __restrict__ br1, const float* __restrict__ bn1, const float* __restrict__ bo1,
    float* __restrict__ Mf, float* __restrict__ bias,
    float* __restrict__ out)
{
    const int bx  = blockIdx.x;
    const int tid = threadIdx.x;

    if (bx >= SETUP_BLOCKS) {
        // ---- pure streaming copy, exact-fit, unpredicated ----
        const int cb = bx - SETUP_BLOCKS;          // 0 .. 6249
        const vf4* __restrict__ p0 = (const vf4*)prev0;
        const vf4* __restrict__ p1 = (const vf4*)prev1;
        vf4* __restrict__ o4 = (vf4*)out;

        const int u0 = cb * 8;                     // first chunk index (0 .. 49,992)

        vf4 v[8];
        #pragma unroll
        for (int i = 0; i < 8; ++i) {
            const int u    = u0 + i;
            const int side = (u >= CHUNKS_PER_SIDE);   // chunk-uniform (scalar)
            const vf4* p   = side ? p1 : p0;
            const size_t src = (size_t)(u - side * CHUNKS_PER_SIDE) * CHUNK_F4 + tid;
            v[i] = __builtin_nontemporal_load(p + src);
        }
        #pragma unroll
        for (int i = 0; i < 8; ++i) {
            const size_t dst = (size_t)(u0 + i) * CHUNK_F4 + tid;
            __builtin_nontemporal_store(v[i], o4 + dst);
        }
        return;
    }

    // ---- setup: fold affine chain into Mf[side][2*DIM][DIM] + bias[side][DIM]
    const int s = (bx >= 257) ? 1 : 0;
    const int k = bx - s * 257;
    const float* Wr = s ? Wr1 : Wr0;
    const float* Wn = s ? Wn1 : Wn0;
    const float* Wo = s ? Wo1 : Wo0;

    if (k < 2 * DIM) {
        __shared__ float w[HID];
        const float* wrow = (k < DIM) ? (Wr + k * HID) : (Wn + (k - DIM) * HID);
        const float* wo   = (k < DIM) ? Wo : (Wo + HID * DIM);
        w[tid] = wrow[tid];          // 256 threads stage the full 256-wide row
        __syncthreads();
        if (tid < DIM) {
            float acc = 0.f;
            #pragma unroll 8
            for (int h = 0; h < HID; ++h) acc += w[h] * wo[h * DIM + tid];
            Mf[((s << 8) + k) * DIM + tid] = acc;
        }
    } else if (tid < DIM) {
        // bias fold (one block per side, no barrier in this branch)
        const float* br = s ? br1 : br0;
        const float* bn = s ? bn1 : bn0;
        const float* bo = s ? bo1 : bo0;
        float acc = bo[tid];
        for (int h = 0; h < HID; ++h) acc += br[h] * Wo[h * DIM + tid];
        for (int h = 0; h < HID; ++h) acc += bn[h] * Wo[(HID + h) * DIM + tid];
        bias[s * DIM + tid] = acc;
    }
}

// ---------------------------------------------------------------------------
// Kernel B: update path. Stream-ordered after Kernel A; overwrites the 8192
// rows per side that A already copied (+8.4 MB redundant write ~ 1.3 us).
// Inner loop reads cat via ds_read_b128 (one per row per 4 k-steps) instead
// of 4x ds_read_b32; accumulation order over k is unchanged (bitwise-stable).
// ---------------------------------------------------------------------------
#define RB 32
#define CAT_STRIDE 260   // float4-aligned (260*4%16==0); rg-groups 16 banks apart

__global__ __launch_bounds__(256) void update_kernel(
    const int* __restrict__ ids0, const float* __restrict__ prev0, const float* __restrict__ nig0,
    const int* __restrict__ ids1, const float* __restrict__ prev1, const float* __restrict__ nig1,
    const float* __restrict__ Mf, const float* __restrict__ bias,
    float* __restrict__ out)
{
    const int bx  = blockIdx.x;    // 512 blocks: 256 per side, 32 batch rows each
    const int tid = threadIdx.x;

    const int s = bx >> 8;
    const int*   ids  = s ? ids1  : ids0;
    const float* prev = s ? prev1 : prev0;
    const float* nig  = s ? nig1  : nig0;
    const float* M    = Mf + s * (2 * DIM) * DIM;
    const float* bs   = bias + s * DIM;
    float* outs = out + (size_t)s * SIDE_FLOATS;

    __shared__ int   sid[RB];
    __shared__ float cat[RB][CAT_STRIDE];

    const int b0 = (bx & 255) * RB;

    if (tid < RB) sid[tid] = ids[b0 + tid];
    __syncthreads();

    for (int idx = tid; idx < RB * 64; idx += 256) {
        const int r = idx >> 6;
        const int q = idx & 63;
        float4 v;
        if (q < 32) v = ((const float4*)(prev + (size_t)sid[r] * DIM))[q];
        else        v = ((const float4*)(nig  + (size_t)(b0 + r) * DIM))[q - 32];
        *(float4*)&cat[r][q * 4] = v;
    }
    __syncthreads();

    const int jg = tid & 31;   // 4-col group
    const int rg = tid >> 5;   // 4-row group

    float acc[4][4];
    #pragma unroll
    for (int r = 0; r < 4; ++r)
        #pragma unroll
        for (int c = 0; c < 4; ++c) acc[r][c] = 0.f;

    const float4* M4 = (const float4*)M;
    #pragma unroll 4
    for (int k4 = 0; k4 < 64; ++k4) {
        // one ds_read_b128 per row: k-slice [4*k4, 4*k4+4) of cat
        float ar[4][4];
        #pragma unroll
        for (int r = 0; r < 4; ++r) {
            const float4 t = *(const float4*)&cat[rg * 4 + r][k4 * 4];
            ar[r][0] = t.x; ar[r][1] = t.y; ar[r][2] = t.z; ar[r][3] = t.w;
        }
        #pragma unroll
        for (int kk = 0; kk < 4; ++kk) {
            const float4 m = M4[((k4 * 4 + kk) << 5) + jg];
            #pragma unroll
            for (int r = 0; r < 4; ++r) {
                const float a = ar[r][kk];
                acc[r][0] += a * m.x;
                acc[r][1] += a * m.y;
                acc[r][2] += a * m.z;
                acc[r][3] += a * m.w;
            }
        }
    }

    const float4 bj = ((const float4*)bs)[jg];
    #pragma unroll
    for (int r = 0; r < 4; ++r) {
        const int row = sid[rg * 4 + r];
        float4 v;
        v.x = acc[r][0] + bj.x;
        v.y = acc[r][1] + bj.y;
        v.z = acc[r][2] + bj.z;
        v.w = acc[r][3] + bj.w;
        ((float4*)(outs + (size_t)row * DIM))[jg] = v;
    }
}

// ---------------------------------------------------------------------------
extern "C" void kernel_launch(void* const* d_in, const int* in_sizes, int n_in,
                              void* d_out, int out_size, void* d_ws, size_t ws_size,
                              hipStream_t stream) {
    const int*   src_ids   = (const int*)d_in[0];
    const int*   dst_ids   = (const int*)d_in[1];
    const float* src_prev  = (const float*)d_in[2];
    const float* dst_prev  = (const float*)d_in[3];
    const float* src_nig   = (const float*)d_in[4];
    const float* dst_nig   = (const float*)d_in[5];
    const float* W_src_nig     = (const float*)d_in[6];
    const float* b_src_nig     = (const float*)d_in[7];
    const float* W_src_resize  = (const float*)d_in[8];
    const float* b_src_resize  = (const float*)d_in[9];
    const float* W_src_out     = (const float*)d_in[10];
    const float* b_src_out     = (const float*)d_in[11];
    const float* W_dst_nig     = (const float*)d_in[12];
    const float* b_dst_nig     = (const float*)d_in[13];
    const float* W_dst_resize  = (const float*)d_in[14];
    const float* b_dst_resize  = (const float*)d_in[15];
    const float* W_dst_out     = (const float*)d_in[16];
    const float* b_dst_out     = (const float*)d_in[17];

    float* out  = (float*)d_out;
    float* Mf   = (float*)d_ws;                       // 2*256*128 floats
    float* bias = Mf + 2 * (2 * DIM) * DIM;           // 2*128 floats

    // 1) streaming copy prev->out (both sides) with the weight-fold hidden
    //    under it (setup blocks dispatched first, finish early)
    copy_setup_kernel<<<SETUP_BLOCKS + COPY_BLOCKS, 256, 0, stream>>>(
        src_prev, dst_prev,
        W_src_resize, W_src_nig, W_src_out, b_src_resize, b_src_nig, b_src_out,
        W_dst_resize, W_dst_nig, W_dst_out, b_dst_resize, b_dst_nig, b_dst_out,
        Mf, bias, out);

    // 2) compute + scatter the 8192 updated rows per side (overwrites)
    update_kernel<<<512, 256, 0, stream>>>(
        src_ids, src_prev, src_nig,
        dst_ids, dst_prev, dst_nig,
        Mf, bias, out);
}